// Round 12
// baseline (405.845 us; speedup 1.0000x reference)
//
#include <hip/hip_runtime.h>
#include <math.h>

#define N_NODES  30000
#define N_EDGES  240000
#define E_TOT    270000   // N_EDGES + N_NODES self loops
#define N_GRAPHS 300
#define NCH      118      // cdiv(N_NODES, 256)

typedef _Float16 half8 __attribute__((ext_vector_type(8)));
typedef _Float16 half4 __attribute__((ext_vector_type(4)));
typedef _Float16 half2v __attribute__((ext_vector_type(2)));
typedef float float4v __attribute__((ext_vector_type(4)));

static inline int cdiv(int a, int b) { return (a + b - 1) / b; }

// ---------------------------------------------------------------------------
// K1: degree histogram + ALL weight transposes + input layer (K=5 GEMM).
// (deg/cnt zeroed by a hipMemsetAsync node before this kernel.)
// ---------------------------------------------------------------------------
__device__ inline void wp_dev(const float* __restrict__ W, _Float16* __restrict__ Wt,
                              int K, int CO, int gtid, int T) {
    int tot = K * CO;
    for (int i = gtid; i < tot; i += T) {
        int k = i / CO, c = i - k * CO;
        Wt[(size_t)c * K + k] = (_Float16)W[i];
    }
}

__global__ void hist_wprep_input(const int* __restrict__ ei, int* __restrict__ deg,
                                 const float* __restrict__ x, const float* __restrict__ w_in,
                                 const float* __restrict__ b_in, const float* __restrict__ bn_in,
                                 _Float16* __restrict__ a16,
                                 const float* __restrict__ w1l, const float* __restrict__ w1r,
                                 const float* __restrict__ w2l, const float* __restrict__ w2r,
                                 const float* __restrict__ w3l, const float* __restrict__ w3r,
                                 _Float16* __restrict__ t1l, _Float16* __restrict__ t1r,
                                 _Float16* __restrict__ t2l, _Float16* __restrict__ t2r,
                                 _Float16* __restrict__ t3l, _Float16* __restrict__ t3r) {
    int gtid = blockIdx.x * blockDim.x + threadIdx.x;
    int T = gridDim.x * blockDim.x;
    for (int e = gtid; e < E_TOT; e += T) {
        int d = (e < N_EDGES) ? ei[N_EDGES + e] : e - N_EDGES;
        atomicAdd(&deg[d], 1);
    }
    wp_dev(w1l, t1l, 64, 256, gtid, T);
    wp_dev(w1r, t1r, 64, 256, gtid, T);
    wp_dev(w2l, t2l, 256, 256, gtid, T);
    wp_dev(w2r, t2r, 256, 256, gtid, T);
    wp_dev(w3l, t3l, 256, 128, gtid, T);
    wp_dev(w3r, t3r, 256, 128, gtid, T);

    int lane = threadIdx.x & 63;
    int wv = blockIdx.x * (blockDim.x >> 6) + (threadIdx.x >> 6);
    int NW = gridDim.x * (blockDim.x >> 6);
    float g = bn_in[lane], be = bn_in[64 + lane];
    float m = bn_in[128 + lane], va = bn_in[192 + lane];
    float rs = rsqrtf(va + 1e-5f);
    float wcol[5];
#pragma unroll
    for (int ci = 0; ci < 5; ++ci) wcol[ci] = w_in[ci * 64 + lane];
    float bb = b_in[lane];
    for (int n = wv; n < N_NODES; n += NW) {
        float xv = (lane < 5) ? x[n * 5 + lane] : 0.f;
        float acc = bb;
#pragma unroll
        for (int ci = 0; ci < 5; ++ci)
            acc = fmaf(__shfl(xv, ci, 64), wcol[ci], acc);
        acc = g * (acc - m) * rs + be;
        a16[(size_t)n * 64 + lane] = (_Float16)fmaxf(acc, 0.f);
    }
}

// ---------------------------------------------------------------------------
// K2: one-launch scan. Block b sums deg[0..b*256) (L2-resident) + local
// chunk scan -> row_start. Block 0 binary-searches gstart (batch sorted).
// ---------------------------------------------------------------------------
__global__ __launch_bounds__(256)
void scan_all(const int* __restrict__ deg, const int* __restrict__ batch,
              int* __restrict__ row_start, int* __restrict__ gstart) {
    __shared__ int red[256];
    __shared__ int s[256];
    const int b = blockIdx.x, t = threadIdx.x;
    int pre = 0;
    for (int i = t; i < b * 256; i += 256) pre += deg[i];
    red[t] = pre;
    __syncthreads();
    for (int off = 128; off; off >>= 1) {
        if (t < off) red[t] += red[t + off];
        __syncthreads();
    }
    int base = red[0];
    int gid = b * 256 + t;
    int v = (gid < N_NODES) ? deg[gid] : 0;
    s[t] = v;
    __syncthreads();
    for (int off = 1; off < 256; off <<= 1) {
        int u = (t >= off) ? s[t - off] : 0;
        __syncthreads();
        s[t] += u;
        __syncthreads();
    }
    if (gid < N_NODES) row_start[gid] = base + s[t] - v;
    if (b == 0 && t == 0) row_start[N_NODES] = E_TOT;
    if (b == 0) {
        for (int g = t; g <= N_GRAPHS; g += 256) {
            int lo = 0, hi = N_NODES;
            while (lo < hi) {
                int mid = (lo + hi) >> 1;
                if (batch[mid] < g) lo = mid + 1;
                else                hi = mid;
            }
            gstart[g] = lo;
        }
    }
}

// ---------------------------------------------------------------------------
// MFMA f16 pair GEMM (fp32 accumulate). SCAT=1 adds a blockIdx.y slice that
// performs the CSR scatter (independent work, hides under the GEMM).
// ---------------------------------------------------------------------------
template<int K, int COUT, int SCAT>
__global__ __launch_bounds__(256, 3)
void gemm_mfma(const _Float16* __restrict__ A,
               const _Float16* __restrict__ Wtl, const float* __restrict__ bl,
               const _Float16* __restrict__ Wtr, const float* __restrict__ br,
               _Float16* __restrict__ outl, _Float16* __restrict__ outr,
               const int* __restrict__ ei, const int* __restrict__ row_start,
               int* __restrict__ cnt, int* __restrict__ esrc, int N) {
    constexpr int BM = 128, BN = 128, BK = 64;
    constexpr int LDK = BK + 8;
    constexpr int CSL = COUT / BN > 0 ? COUT / BN : 1;
    if (SCAT && blockIdx.y == 2 * CSL) {       // scatter slice
        int gtid = blockIdx.x * blockDim.x + threadIdx.x;
        int T = gridDim.x * blockDim.x;
        for (int e = gtid; e < E_TOT; e += T) {
            int s, d;
            if (e < N_EDGES) { s = ei[e]; d = ei[N_EDGES + e]; }
            else             { s = e - N_EDGES; d = s; }
            int slot = row_start[d] + atomicAdd(&cnt[d], 1);
            esrc[slot] = s;
        }
        return;
    }
    __shared__ _Float16 As[BM][LDK];
    __shared__ _Float16 Bs[BN][LDK];
    const int tid  = threadIdx.x;
    const int wave = tid >> 6;
    const int lane = tid & 63;
    const int l15  = lane & 15;
    const int lq   = lane >> 4;
    const int n0   = blockIdx.x * BM;
    const int sel  = blockIdx.y / CSL;
    const int col0 = (blockIdx.y % CSL) * BN;
    const _Float16* Wt = sel ? Wtr : Wtl;
    const float* bias  = sel ? br : bl;
    _Float16* out      = sel ? outr : outl;

    float4v acc[2][8];
#pragma unroll
    for (int mi = 0; mi < 2; ++mi)
#pragma unroll
        for (int nt = 0; nt < 8; ++nt)
#pragma unroll
            for (int r = 0; r < 4; ++r) acc[mi][nt][r] = 0.f;

    for (int kt = 0; kt < K; kt += BK) {
#pragma unroll
        for (int p = 0; p < 4; ++p) {
            int idx = p * 256 + tid;
            int row = idx >> 3;
            int ch  = (idx & 7) * 8;
            int gn  = n0 + row;
            half8 v = {};
            if (gn < N) v = *(const half8*)(A + (size_t)gn * K + kt + ch);
            *(half8*)(&As[row][ch]) = v;
        }
#pragma unroll
        for (int p = 0; p < 4; ++p) {
            int idx = p * 256 + tid;
            int row = idx >> 3;
            int ch  = (idx & 7) * 8;
            half8 v = *(const half8*)(Wt + (size_t)(col0 + row) * K + kt + ch);
            *(half8*)(&Bs[row][ch]) = v;
        }
        __syncthreads();
#pragma unroll
        for (int kk = 0; kk < BK; kk += 32) {
            half8 af0 = *(const half8*)(&As[wave * 32 + l15][kk + lq * 8]);
            half8 af1 = *(const half8*)(&As[wave * 32 + 16 + l15][kk + lq * 8]);
#pragma unroll
            for (int nt = 0; nt < 8; ++nt) {
                half8 bf = *(const half8*)(&Bs[nt * 16 + l15][kk + lq * 8]);
                acc[0][nt] = __builtin_amdgcn_mfma_f32_16x16x32_f16(af0, bf, acc[0][nt], 0, 0, 0);
                acc[1][nt] = __builtin_amdgcn_mfma_f32_16x16x32_f16(af1, bf, acc[1][nt], 0, 0, 0);
            }
        }
        __syncthreads();
    }
#pragma unroll
    for (int mi = 0; mi < 2; ++mi)
#pragma unroll
        for (int nt = 0; nt < 8; ++nt) {
            int col = col0 + nt * 16 + l15;
            float bv = bias[col];
#pragma unroll
            for (int r = 0; r < 4; ++r) {
                int row = n0 + wave * 32 + mi * 16 + lq * 4 + r;
                if (row < N)
                    out[(size_t)row * COUT + col] = (_Float16)(acc[mi][nt][r] + bv);
            }
        }
}

// ---------------------------------------------------------------------------
// GATv2 gather (H=4, HC=256): QUARTERED wave. Four 16-lane quarters, one
// edge per quarter; lane covers 16 contiguous channels ((lane&15)*16), all
// of one head -> per-head dot reduces in 2 hops (xor 1,2) and ONE exp per
// lane per 4-edge step. Max-free softmax (logits BN-bounded) makes partial
// sums order-independent; quarters combine once per node (xor 16,32).
// ---------------------------------------------------------------------------
__global__ __launch_bounds__(256)
void gat_gather4(const _Float16* __restrict__ xl, const _Float16* __restrict__ xr,
                 const int* __restrict__ row_start, const int* __restrict__ esrc,
                 const float* __restrict__ att, const float* __restrict__ gbias,
                 const float* __restrict__ bnp, _Float16* __restrict__ out) {
    constexpr int HC = 256, PER = 16;
    int node = (blockIdx.x * blockDim.x + threadIdx.x) >> 6;
    int lane = threadIdx.x & 63;
    if (node >= N_NODES) return;
    const int q    = lane >> 4;            // quarter 0..3 (edge slot)
    const int base = (lane & 15) * PER;    // 16 channels, single head

    float rr[PER], av[PER], acc[PER];
    {
        half8 r0 = *(const half8*)(xr + (size_t)node * HC + base);
        half8 r1 = *(const half8*)(xr + (size_t)node * HC + base + 8);
#pragma unroll
        for (int k = 0; k < 8; ++k) { rr[k] = (float)r0[k]; rr[8 + k] = (float)r1[k]; }
        *(float4*)(av)      = *(const float4*)(att + base);
        *(float4*)(av + 4)  = *(const float4*)(att + base + 4);
        *(float4*)(av + 8)  = *(const float4*)(att + base + 8);
        *(float4*)(av + 12) = *(const float4*)(att + base + 12);
    }
#pragma unroll
    for (int k = 0; k < PER; ++k) acc[k] = 0.f;

    float l = 0.f;
    const int j0 = row_start[node], j1 = row_start[node + 1];
    for (int jc = j0; jc < j1; jc += 64) {
        int nedge = min(64, j1 - jc);
        int ev = (jc + lane < j1) ? esrc[jc + lane] : 0;
        for (int jj = 0; jj < nedge; jj += 4) {
            int idx = jj + q;
            bool val = idx < nedge;
            int s = __shfl(ev, val ? idx : jj, 64);
            float xs[PER];
            {
                half8 x0 = *(const half8*)(xl + (size_t)s * HC + base);
                half8 x1 = *(const half8*)(xl + (size_t)s * HC + base + 8);
#pragma unroll
                for (int k = 0; k < 8; ++k) { xs[k] = (float)x0[k]; xs[8 + k] = (float)x1[k]; }
            }
            float pp = 0.f;
#pragma unroll
            for (int k = 0; k < PER; ++k) {
                float v = xs[k] + rr[k];
                v = (v > 0.f) ? v : 0.2f * v;              // leaky_relu 0.2
                pp = fmaf(v, av[k], pp);
            }
            pp += __shfl_xor(pp, 1, 64);                   // head dot: 4 lanes
            pp += __shfl_xor(pp, 2, 64);
            float w = val ? __expf(pp) : 0.f;
            l += w;
#pragma unroll
            for (int k = 0; k < PER; ++k) acc[k] = fmaf(w, xs[k], acc[k]);
        }
    }
    // combine quarters (disjoint edge sets, same channels/heads)
    l += __shfl_xor(l, 16, 64);
    l += __shfl_xor(l, 32, 64);
#pragma unroll
    for (int k = 0; k < PER; ++k) {
        acc[k] += __shfl_xor(acc[k], 16, 64);
        acc[k] += __shfl_xor(acc[k], 32, 64);
    }
    if (q == 0) {
        float inv = 1.f / (l + 1e-16f);
        half8 o0, o1;
#pragma unroll
        for (int k = 0; k < PER; ++k) {
            float v = fmaf(acc[k], inv, gbias[base + k]);
            float g  = bnp[base + k], be = bnp[HC + base + k];
            float mm = bnp[2 * HC + base + k], va = bnp[3 * HC + base + k];
            v = g * (v - mm) * rsqrtf(va + 1e-5f) + be;
            v = (v > 0.f) ? v : (__expf(v) - 1.f);         // elu
            if (k < 8) o0[k] = (_Float16)v; else o1[k - 8] = (_Float16)v;
        }
        *(half8*)(out + (size_t)node * HC + base)     = o0;
        *(half8*)(out + (size_t)node * HC + base + 8) = o1;
    }
}

// ---------------------------------------------------------------------------
// GATv2 gather (H=1, C=128): dual-edge wave (two 32-lane halves), max-free.
// ---------------------------------------------------------------------------
__global__ __launch_bounds__(256)
void gat_gather1(const _Float16* __restrict__ xl, const _Float16* __restrict__ xr,
                 const int* __restrict__ row_start, const int* __restrict__ esrc,
                 const float* __restrict__ att, const float* __restrict__ gbias,
                 const float* __restrict__ bnp, float* __restrict__ out) {
    constexpr int HC = 128, PER = 4;
    int node = (blockIdx.x * blockDim.x + threadIdx.x) >> 6;
    int lane = threadIdx.x & 63;
    if (node >= N_NODES) return;
    const int half = lane >> 5;
    const int base = (lane & 31) * PER;

    float rr[PER], av[PER], acc[PER];
    {
        half4 rv = *(const half4*)(xr + (size_t)node * HC + base);
#pragma unroll
        for (int k = 0; k < PER; ++k) rr[k] = (float)rv[k];
        *(float4*)av = *(const float4*)(att + base);
    }
#pragma unroll
    for (int k = 0; k < PER; ++k) acc[k] = 0.f;

    float l = 0.f;
    const int j0 = row_start[node], j1 = row_start[node + 1];
    for (int jc = j0; jc < j1; jc += 64) {
        int nedge = min(64, j1 - jc);
        int ev = (jc + lane < j1) ? esrc[jc + lane] : 0;
        for (int jj = 0; jj < nedge; jj += 8) {          // 8 edges: 4 per half
            int s[4];
            bool val[4];
#pragma unroll
            for (int u = 0; u < 4; ++u) {
                int idx = jj + 2 * u + half;
                val[u] = idx < nedge;
                s[u] = __shfl(ev, val[u] ? idx : jj, 64);
            }
            float xs[4][PER];
#pragma unroll
            for (int u = 0; u < 4; ++u) {
                half4 xv = *(const half4*)(xl + (size_t)s[u] * HC + base);
#pragma unroll
                for (int k = 0; k < PER; ++k) xs[u][k] = (float)xv[k];
            }
            float pz[4];
#pragma unroll
            for (int u = 0; u < 4; ++u) {
                float pp = 0.f;
#pragma unroll
                for (int k = 0; k < PER; ++k) {
                    float v = xs[u][k] + rr[k];
                    v = (v > 0.f) ? v : 0.2f * v;
                    pp = fmaf(v, av[k], pp);
                }
                pz[u] = pp;
            }
#pragma unroll
            for (int off = 16; off; off >>= 1) {         // 5 hops, in-half
#pragma unroll
                for (int u = 0; u < 4; ++u) pz[u] += __shfl_xor(pz[u], off, 64);
            }
            float w[4];
#pragma unroll
            for (int u = 0; u < 4; ++u) w[u] = val[u] ? __expf(pz[u]) : 0.f;
            l += (w[0] + w[1]) + (w[2] + w[3]);
#pragma unroll
            for (int k = 0; k < PER; ++k)
                acc[k] += fmaf(w[0], xs[0][k],
                          fmaf(w[1], xs[1][k],
                          fmaf(w[2], xs[2][k], w[3] * xs[3][k])));
        }
    }
    l += __shfl_xor(l, 32, 64);
#pragma unroll
    for (int k = 0; k < PER; ++k) acc[k] += __shfl_xor(acc[k], 32, 64);

    if (half == 0) {
        float inv = 1.f / (l + 1e-16f);
        float o[PER];
#pragma unroll
        for (int k = 0; k < PER; ++k) {
            float v = fmaf(acc[k], inv, gbias[base + k]);
            float g  = bnp[base + k], be = bnp[HC + base + k];
            float mm = bnp[2 * HC + base + k], va = bnp[3 * HC + base + k];
            v = g * (v - mm) * rsqrtf(va + 1e-5f) + be;
            o[k] = (v > 0.f) ? v : (__expf(v) - 1.f);
        }
        *(float4*)(out + (size_t)node * HC + base) = *(float4*)o;
    }
}

// ---------------------------------------------------------------------------
// K9: fused pooling + classifier, one block (128 threads) per graph
// ---------------------------------------------------------------------------
__global__ void pool_cls(const float* __restrict__ h, const int* __restrict__ gstart,
                         const float* __restrict__ w1, const float* __restrict__ b1,
                         const float* __restrict__ bnp,
                         const float* __restrict__ w2, const float* __restrict__ b2,
                         const float* __restrict__ w3, const float* __restrict__ b3,
                         float* __restrict__ out) {
    __shared__ float sg[256];
    __shared__ float sz1[128];
    __shared__ float sz2[64];
    __shared__ float sz3[2];
    int g = blockIdx.x, t = threadIdx.x;
    int a = gstart[g], b = gstart[g + 1];
    float sum = 0.f, mx = -INFINITY;
    for (int i = a; i < b; ++i) {
        float v = h[(size_t)i * 128 + t];
        sum += v;
        mx = fmaxf(mx, v);
    }
    sg[t]       = sum / fmaxf((float)(b - a), 1.f);
    sg[128 + t] = (b > a) ? mx : 0.f;
    __syncthreads();
    float acc = b1[t];
    for (int i = 0; i < 256; ++i) acc += sg[i] * w1[i * 128 + t];
    float ga = bnp[t], be = bnp[128 + t], m = bnp[256 + t], va = bnp[384 + t];
    acc = ga * (acc - m) * rsqrtf(va + 1e-5f) + be;
    sz1[t] = fmaxf(acc, 0.f);
    __syncthreads();
    if (t < 64) {
        float a2 = b2[t];
        for (int i = 0; i < 128; ++i) a2 += sz1[i] * w2[i * 64 + t];
        sz2[t] = fmaxf(a2, 0.f);
    }
    __syncthreads();
    if (t < 2) {
        float a3 = b3[t];
        for (int i = 0; i < 64; ++i) a3 += sz2[i] * w3[i * 2 + t];
        sz3[t] = a3;
    }
    __syncthreads();
    if (t < 2) {
        float mm = fmaxf(sz3[0], sz3[1]);
        float lse = mm + logf(expf(sz3[0] - mm) + expf(sz3[1] - mm));
        out[g * 2 + t] = sz3[t] - lse;
    }
}

// ---------------------------------------------------------------------------
// launch: 1 memset + 9 kernels
// ---------------------------------------------------------------------------
extern "C" void kernel_launch(void* const* d_in, const int* in_sizes, int n_in,
                              void* d_out, int out_size, void* d_ws, size_t ws_size,
                              hipStream_t stream) {
    const float* x       = (const float*)d_in[0];
    const int*   ei      = (const int*)d_in[1];
    const int*   batch   = (const int*)d_in[2];
    const float* w_in    = (const float*)d_in[3];
    const float* b_in    = (const float*)d_in[4];
    const float* bn_in   = (const float*)d_in[5];
    const float* g1_wl   = (const float*)d_in[6];
    const float* g1_bl   = (const float*)d_in[7];
    const float* g1_wr   = (const float*)d_in[8];
    const float* g1_br   = (const float*)d_in[9];
    const float* g1_att  = (const float*)d_in[10];
    const float* g1_bias = (const float*)d_in[11];
    const float* bn1     = (const float*)d_in[12];
    const float* g2_wl   = (const float*)d_in[13];
    const float* g2_bl   = (const float*)d_in[14];
    const float* g2_wr   = (const float*)d_in[15];
    const float* g2_br   = (const float*)d_in[16];
    const float* g2_att  = (const float*)d_in[17];
    const float* g2_bias = (const float*)d_in[18];
    const float* bn2     = (const float*)d_in[19];
    const float* g3_wl   = (const float*)d_in[20];
    const float* g3_bl   = (const float*)d_in[21];
    const float* g3_wr   = (const float*)d_in[22];
    const float* g3_br   = (const float*)d_in[23];
    const float* g3_att  = (const float*)d_in[24];
    const float* g3_bias = (const float*)d_in[25];
    const float* bn3     = (const float*)d_in[26];
    const float* c_w1    = (const float*)d_in[27];
    const float* c_b1    = (const float*)d_in[28];
    const float* c_bn    = (const float*)d_in[29];
    const float* c_w2    = (const float*)d_in[30];
    const float* c_b2    = (const float*)d_in[31];
    const float* c_w3    = (const float*)d_in[32];
    const float* c_b3    = (const float*)d_in[33];
    float* out = (float*)d_out;

    // ---- workspace layout
    const size_t NHC = (size_t)N_NODES * 256;
    _Float16* a16  = (_Float16*)d_ws;
    _Float16* xl16 = a16 + NHC;
    _Float16* xr16 = xl16 + NHC;
    _Float16* wt = xr16 + NHC;
    _Float16* wt1l = wt;            _Float16* wt1r = wt + 16384;
    _Float16* wt2l = wt + 32768;    _Float16* wt2r = wt + 98304;
    _Float16* wt3l = wt + 163840;   _Float16* wt3r = wt + 196608;
    float* fbase = (float*)(wt + 262144);
    float* bufD = fbase;
    int* iw = (int*)(bufD + (size_t)N_NODES * 128);
    int* deg       = iw;            int* cnt    = iw + 30000;   // contiguous pair
    int* row_start = iw + 90128;
    int* esrc      = iw + 120129;
    int* gstart    = iw + 390429;

    const int BT = 256;
    const int NT128 = cdiv(N_NODES, 128);      // 235

    // N0: zero deg+cnt
    hipMemsetAsync(deg, 0, 60000 * sizeof(int), stream);

    // K1: histogram + weight prep + input layer
    hist_wprep_input<<<1024, BT, 0, stream>>>(ei, deg, x, w_in, b_in, bn_in, a16,
                                              g1_wl, g1_wr, g2_wl, g2_wr, g3_wl, g3_wr,
                                              wt1l, wt1r, wt2l, wt2r, wt3l, wt3r);
    // K2: row_start scan + gstart binary search
    scan_all<<<NCH, 256, 0, stream>>>(deg, batch, row_start, gstart);

    // K3: GAT layer-1 GEMM + fused CSR scatter (extra y-slice)
    gemm_mfma<64, 256, 1><<<dim3(NT128, 5), 256, 0, stream>>>(
        a16, wt1l, g1_bl, wt1r, g1_br, xl16, xr16, ei, row_start, cnt, esrc, N_NODES);
    // K4: gather 1 (quartered)
    gat_gather4<<<cdiv(N_NODES * 64, BT), BT, 0, stream>>>(
        xl16, xr16, row_start, esrc, g1_att, g1_bias, bn1, a16);

    // K5/K6: GAT layer 2
    gemm_mfma<256, 256, 0><<<dim3(NT128, 4), 256, 0, stream>>>(
        a16, wt2l, g2_bl, wt2r, g2_br, xl16, xr16, nullptr, nullptr, nullptr, nullptr, N_NODES);
    gat_gather4<<<cdiv(N_NODES * 64, BT), BT, 0, stream>>>(
        xl16, xr16, row_start, esrc, g2_att, g2_bias, bn2, a16);

    // K7/K8: GAT layer 3 (dual-edge gather emits f32 for pooling)
    gemm_mfma<256, 128, 0><<<dim3(NT128, 2), 256, 0, stream>>>(
        a16, wt3l, g3_bl, wt3r, g3_br, xl16, xr16, nullptr, nullptr, nullptr, nullptr, N_NODES);
    gat_gather1<<<cdiv(N_NODES * 64, BT), BT, 0, stream>>>(
        xl16, xr16, row_start, esrc, g3_att, g3_bias, bn3, bufD);

    // K9: fused pooling + classifier
    pool_cls<<<N_GRAPHS, 128, 0, stream>>>(bufD, gstart, c_w1, c_b1, c_bn,
                                           c_w2, c_b2, c_w3, c_b3, out);
}

// Round 13
// 379.113 us; speedup vs baseline: 1.0705x; 1.0705x over previous
//
#include <hip/hip_runtime.h>
#include <math.h>

#define N_NODES  30000
#define N_EDGES  240000
#define E_TOT    270000   // N_EDGES + N_NODES self loops
#define N_GRAPHS 300
#define NCH      118      // cdiv(N_NODES, 256)

typedef _Float16 half8 __attribute__((ext_vector_type(8)));
typedef _Float16 half4 __attribute__((ext_vector_type(4)));
typedef float float4v __attribute__((ext_vector_type(4)));

static inline int cdiv(int a, int b) { return (a + b - 1) / b; }

// ---------------------------------------------------------------------------
// K1: degree histogram + ALL weight transposes + input layer (K=5 GEMM).
// (deg/cnt zeroed by a hipMemsetAsync node before this kernel.)
// ---------------------------------------------------------------------------
__device__ inline void wp_dev(const float* __restrict__ W, _Float16* __restrict__ Wt,
                              int K, int CO, int gtid, int T) {
    int tot = K * CO;
    for (int i = gtid; i < tot; i += T) {
        int k = i / CO, c = i - k * CO;
        Wt[(size_t)c * K + k] = (_Float16)W[i];
    }
}

__global__ void hist_wprep_input(const int* __restrict__ ei, int* __restrict__ deg,
                                 const float* __restrict__ x, const float* __restrict__ w_in,
                                 const float* __restrict__ b_in, const float* __restrict__ bn_in,
                                 _Float16* __restrict__ a16,
                                 const float* __restrict__ w1l, const float* __restrict__ w1r,
                                 const float* __restrict__ w2l, const float* __restrict__ w2r,
                                 const float* __restrict__ w3l, const float* __restrict__ w3r,
                                 _Float16* __restrict__ t1l, _Float16* __restrict__ t1r,
                                 _Float16* __restrict__ t2l, _Float16* __restrict__ t2r,
                                 _Float16* __restrict__ t3l, _Float16* __restrict__ t3r) {
    int gtid = blockIdx.x * blockDim.x + threadIdx.x;
    int T = gridDim.x * blockDim.x;
    for (int e = gtid; e < E_TOT; e += T) {
        int d = (e < N_EDGES) ? ei[N_EDGES + e] : e - N_EDGES;
        atomicAdd(&deg[d], 1);
    }
    wp_dev(w1l, t1l, 64, 256, gtid, T);
    wp_dev(w1r, t1r, 64, 256, gtid, T);
    wp_dev(w2l, t2l, 256, 256, gtid, T);
    wp_dev(w2r, t2r, 256, 256, gtid, T);
    wp_dev(w3l, t3l, 256, 128, gtid, T);
    wp_dev(w3r, t3r, 256, 128, gtid, T);

    int lane = threadIdx.x & 63;
    int wv = blockIdx.x * (blockDim.x >> 6) + (threadIdx.x >> 6);
    int NW = gridDim.x * (blockDim.x >> 6);
    float g = bn_in[lane], be = bn_in[64 + lane];
    float m = bn_in[128 + lane], va = bn_in[192 + lane];
    float rs = rsqrtf(va + 1e-5f);
    float wcol[5];
#pragma unroll
    for (int ci = 0; ci < 5; ++ci) wcol[ci] = w_in[ci * 64 + lane];
    float bb = b_in[lane];
    for (int n = wv; n < N_NODES; n += NW) {
        float xv = (lane < 5) ? x[n * 5 + lane] : 0.f;
        float acc = bb;
#pragma unroll
        for (int ci = 0; ci < 5; ++ci)
            acc = fmaf(__shfl(xv, ci, 64), wcol[ci], acc);
        acc = g * (acc - m) * rs + be;
        a16[(size_t)n * 64 + lane] = (_Float16)fmaxf(acc, 0.f);
    }
}

// ---------------------------------------------------------------------------
// K2: one-launch scan. Block b sums deg[0..b*256) (L2-resident) + local
// chunk scan -> row_start. Block 0 binary-searches gstart (batch sorted).
// ---------------------------------------------------------------------------
__global__ __launch_bounds__(256)
void scan_all(const int* __restrict__ deg, const int* __restrict__ batch,
              int* __restrict__ row_start, int* __restrict__ gstart) {
    __shared__ int red[256];
    __shared__ int s[256];
    const int b = blockIdx.x, t = threadIdx.x;
    int pre = 0;
    for (int i = t; i < b * 256; i += 256) pre += deg[i];
    red[t] = pre;
    __syncthreads();
    for (int off = 128; off; off >>= 1) {
        if (t < off) red[t] += red[t + off];
        __syncthreads();
    }
    int base = red[0];
    int gid = b * 256 + t;
    int v = (gid < N_NODES) ? deg[gid] : 0;
    s[t] = v;
    __syncthreads();
    for (int off = 1; off < 256; off <<= 1) {
        int u = (t >= off) ? s[t - off] : 0;
        __syncthreads();
        s[t] += u;
        __syncthreads();
    }
    if (gid < N_NODES) row_start[gid] = base + s[t] - v;
    if (b == 0 && t == 0) row_start[N_NODES] = E_TOT;
    if (b == 0) {
        for (int g = t; g <= N_GRAPHS; g += 256) {
            int lo = 0, hi = N_NODES;
            while (lo < hi) {
                int mid = (lo + hi) >> 1;
                if (batch[mid] < g) lo = mid + 1;
                else                hi = mid;
            }
            gstart[g] = lo;
        }
    }
}

// ---------------------------------------------------------------------------
// MFMA f16 pair GEMM (fp32 accumulate). SCAT=1 adds a blockIdx.y slice that
// performs the CSR scatter (independent work, hides under the GEMM).
// ---------------------------------------------------------------------------
template<int K, int COUT, int SCAT>
__global__ __launch_bounds__(256, 3)
void gemm_mfma(const _Float16* __restrict__ A,
               const _Float16* __restrict__ Wtl, const float* __restrict__ bl,
               const _Float16* __restrict__ Wtr, const float* __restrict__ br,
               _Float16* __restrict__ outl, _Float16* __restrict__ outr,
               const int* __restrict__ ei, const int* __restrict__ row_start,
               int* __restrict__ cnt, int* __restrict__ esrc, int N) {
    constexpr int BM = 128, BN = 128, BK = 64;
    constexpr int LDK = BK + 8;
    constexpr int CSL = COUT / BN > 0 ? COUT / BN : 1;
    if (SCAT && blockIdx.y == 2 * CSL) {       // scatter slice
        int gtid = blockIdx.x * blockDim.x + threadIdx.x;
        int T = gridDim.x * blockDim.x;
        for (int e = gtid; e < E_TOT; e += T) {
            int s, d;
            if (e < N_EDGES) { s = ei[e]; d = ei[N_EDGES + e]; }
            else             { s = e - N_EDGES; d = s; }
            int slot = row_start[d] + atomicAdd(&cnt[d], 1);
            esrc[slot] = s;
        }
        return;
    }
    __shared__ _Float16 As[BM][LDK];
    __shared__ _Float16 Bs[BN][LDK];
    const int tid  = threadIdx.x;
    const int wave = tid >> 6;
    const int lane = tid & 63;
    const int l15  = lane & 15;
    const int lq   = lane >> 4;
    const int n0   = blockIdx.x * BM;
    const int sel  = blockIdx.y / CSL;
    const int col0 = (blockIdx.y % CSL) * BN;
    const _Float16* Wt = sel ? Wtr : Wtl;
    const float* bias  = sel ? br : bl;
    _Float16* out      = sel ? outr : outl;

    float4v acc[2][8];
#pragma unroll
    for (int mi = 0; mi < 2; ++mi)
#pragma unroll
        for (int nt = 0; nt < 8; ++nt)
#pragma unroll
            for (int r = 0; r < 4; ++r) acc[mi][nt][r] = 0.f;

    for (int kt = 0; kt < K; kt += BK) {
#pragma unroll
        for (int p = 0; p < 4; ++p) {
            int idx = p * 256 + tid;
            int row = idx >> 3;
            int ch  = (idx & 7) * 8;
            int gn  = n0 + row;
            half8 v = {};
            if (gn < N) v = *(const half8*)(A + (size_t)gn * K + kt + ch);
            *(half8*)(&As[row][ch]) = v;
        }
#pragma unroll
        for (int p = 0; p < 4; ++p) {
            int idx = p * 256 + tid;
            int row = idx >> 3;
            int ch  = (idx & 7) * 8;
            half8 v = *(const half8*)(Wt + (size_t)(col0 + row) * K + kt + ch);
            *(half8*)(&Bs[row][ch]) = v;
        }
        __syncthreads();
#pragma unroll
        for (int kk = 0; kk < BK; kk += 32) {
            half8 af0 = *(const half8*)(&As[wave * 32 + l15][kk + lq * 8]);
            half8 af1 = *(const half8*)(&As[wave * 32 + 16 + l15][kk + lq * 8]);
#pragma unroll
            for (int nt = 0; nt < 8; ++nt) {
                half8 bf = *(const half8*)(&Bs[nt * 16 + l15][kk + lq * 8]);
                acc[0][nt] = __builtin_amdgcn_mfma_f32_16x16x32_f16(af0, bf, acc[0][nt], 0, 0, 0);
                acc[1][nt] = __builtin_amdgcn_mfma_f32_16x16x32_f16(af1, bf, acc[1][nt], 0, 0, 0);
            }
        }
        __syncthreads();
    }
#pragma unroll
    for (int mi = 0; mi < 2; ++mi)
#pragma unroll
        for (int nt = 0; nt < 8; ++nt) {
            int col = col0 + nt * 16 + l15;
            float bv = bias[col];
#pragma unroll
            for (int r = 0; r < 4; ++r) {
                int row = n0 + wave * 32 + mi * 16 + lq * 4 + r;
                if (row < N)
                    out[(size_t)row * COUT + col] = (_Float16)(acc[mi][nt][r] + bv);
            }
        }
}

// ---------------------------------------------------------------------------
// GATv2 gather (H=4, HC=256): HALVED wave, uniform shuffles only.
// Two 32-lane halves, one edge per half; lane covers 8 contiguous channels
// ((lane&31)*8) all of one head -> dot reduces in 3 hops (xor 1,2,4), one
// exp per lane per edge. Edge select = two uniform readlane broadcasts +
// cndmask on half (NO ds_bpermute on the address path — R12 lesson).
// 2x unrolled (4 edges in flight). Max-free softmax (logits BN-bounded);
// halves combine once per node (xor 32).
// ---------------------------------------------------------------------------
__global__ __launch_bounds__(256)
void gat_gather4(const _Float16* __restrict__ xl, const _Float16* __restrict__ xr,
                 const int* __restrict__ row_start, const int* __restrict__ esrc,
                 const float* __restrict__ att, const float* __restrict__ gbias,
                 const float* __restrict__ bnp, _Float16* __restrict__ out) {
    constexpr int HC = 256, PER = 8;
    int node = (blockIdx.x * blockDim.x + threadIdx.x) >> 6;
    int lane = threadIdx.x & 63;
    if (node >= N_NODES) return;
    const int half = lane >> 5;
    const int base = (lane & 31) * PER;    // 8 channels, single head (8 lanes/head)

    float rr[PER], av[PER], acc[PER];
    {
        half8 rv = *(const half8*)(xr + (size_t)node * HC + base);
#pragma unroll
        for (int k = 0; k < PER; ++k) rr[k] = (float)rv[k];
        *(float4*)(av)     = *(const float4*)(att + base);
        *(float4*)(av + 4) = *(const float4*)(att + base + 4);
    }
#pragma unroll
    for (int k = 0; k < PER; ++k) acc[k] = 0.f;

    float l = 0.f;
    const int j0 = row_start[node], j1 = row_start[node + 1];
    for (int jc = j0; jc < j1; jc += 64) {
        int nedge = min(64, j1 - jc);
        int ev = (jc + lane < j1) ? esrc[jc + lane] : 0;
        for (int jj = 0; jj < nedge; jj += 4) {          // 4 edges: 2 per half
            // uniform-index broadcasts (readlane), clamped to valid range
            int i1 = min(jj + 1, nedge - 1);
            int i2 = min(jj + 2, nedge - 1);
            int i3 = min(jj + 3, nedge - 1);
            int sa0 = __shfl(ev, jj, 64);
            int sb0 = __shfl(ev, i1, 64);
            int sa1 = __shfl(ev, i2, 64);
            int sb1 = __shfl(ev, i3, 64);
            int s0 = half ? sb0 : sa0;                   // cndmask, not bpermute
            int s1 = half ? sb1 : sa1;
            bool v0 = (jj + half)     < nedge;
            bool v1 = (jj + 2 + half) < nedge;
            // two independent scattered loads in flight
            half8 xv0 = *(const half8*)(xl + (size_t)s0 * HC + base);
            half8 xv1 = *(const half8*)(xl + (size_t)s1 * HC + base);
            float xs0[PER], xs1[PER];
#pragma unroll
            for (int k = 0; k < PER; ++k) { xs0[k] = (float)xv0[k]; xs1[k] = (float)xv1[k]; }
            float p0 = 0.f, p1 = 0.f;
#pragma unroll
            for (int k = 0; k < PER; ++k) {
                float a0 = xs0[k] + rr[k];
                a0 = (a0 > 0.f) ? a0 : 0.2f * a0;        // leaky_relu 0.2
                p0 = fmaf(a0, av[k], p0);
                float a1 = xs1[k] + rr[k];
                a1 = (a1 > 0.f) ? a1 : 0.2f * a1;
                p1 = fmaf(a1, av[k], p1);
            }
#pragma unroll
            for (int off = 1; off <= 4; off <<= 1) {     // 3 hops, in-head
                p0 += __shfl_xor(p0, off, 64);
                p1 += __shfl_xor(p1, off, 64);
            }
            float w0 = v0 ? __expf(p0) : 0.f;
            float w1 = v1 ? __expf(p1) : 0.f;
            l += w0 + w1;
#pragma unroll
            for (int k = 0; k < PER; ++k)
                acc[k] += fmaf(w0, xs0[k], w1 * xs1[k]);
        }
    }
    // combine the two halves (disjoint edge sets, same channels)
    l += __shfl_xor(l, 32, 64);
#pragma unroll
    for (int k = 0; k < PER; ++k) acc[k] += __shfl_xor(acc[k], 32, 64);

    if (half == 0) {
        float inv = 1.f / (l + 1e-16f);
        half8 ov;
#pragma unroll
        for (int k = 0; k < PER; ++k) {
            float v = fmaf(acc[k], inv, gbias[base + k]);
            float g  = bnp[base + k], be = bnp[HC + base + k];
            float mm = bnp[2 * HC + base + k], va = bnp[3 * HC + base + k];
            v = g * (v - mm) * rsqrtf(va + 1e-5f) + be;
            v = (v > 0.f) ? v : (__expf(v) - 1.f);       // elu
            ov[k] = (_Float16)v;
        }
        *(half8*)(out + (size_t)node * HC + base) = ov;
    }
}

// ---------------------------------------------------------------------------
// GATv2 gather (H=1, C=128): dual-edge wave (two 32-lane halves), max-free,
// uniform shuffles + cndmask select (no bpermute).
// ---------------------------------------------------------------------------
__global__ __launch_bounds__(256)
void gat_gather1(const _Float16* __restrict__ xl, const _Float16* __restrict__ xr,
                 const int* __restrict__ row_start, const int* __restrict__ esrc,
                 const float* __restrict__ att, const float* __restrict__ gbias,
                 const float* __restrict__ bnp, float* __restrict__ out) {
    constexpr int HC = 128, PER = 4;
    int node = (blockIdx.x * blockDim.x + threadIdx.x) >> 6;
    int lane = threadIdx.x & 63;
    if (node >= N_NODES) return;
    const int half = lane >> 5;
    const int base = (lane & 31) * PER;

    float rr[PER], av[PER], acc[PER];
    {
        half4 rv = *(const half4*)(xr + (size_t)node * HC + base);
#pragma unroll
        for (int k = 0; k < PER; ++k) rr[k] = (float)rv[k];
        *(float4*)av = *(const float4*)(att + base);
    }
#pragma unroll
    for (int k = 0; k < PER; ++k) acc[k] = 0.f;

    float l = 0.f;
    const int j0 = row_start[node], j1 = row_start[node + 1];
    for (int jc = j0; jc < j1; jc += 64) {
        int nedge = min(64, j1 - jc);
        int ev = (jc + lane < j1) ? esrc[jc + lane] : 0;
        for (int jj = 0; jj < nedge; jj += 8) {          // 8 edges: 4 per half
            int s[4];
            bool val[4];
#pragma unroll
            for (int u = 0; u < 4; ++u) {
                int ia = jj + 2 * u;
                int ib = min(ia + 1, nedge - 1);
                int sa = __shfl(ev, min(ia, nedge - 1), 64);   // uniform readlane
                int sb = __shfl(ev, ib, 64);                   // uniform readlane
                s[u] = half ? sb : sa;                         // cndmask
                val[u] = (ia + half) < nedge;
            }
            float xs[4][PER];
#pragma unroll
            for (int u = 0; u < 4; ++u) {
                half4 xv = *(const half4*)(xl + (size_t)s[u] * HC + base);
#pragma unroll
                for (int k = 0; k < PER; ++k) xs[u][k] = (float)xv[k];
            }
            float pz[4];
#pragma unroll
            for (int u = 0; u < 4; ++u) {
                float pp = 0.f;
#pragma unroll
                for (int k = 0; k < PER; ++k) {
                    float v = xs[u][k] + rr[k];
                    v = (v > 0.f) ? v : 0.2f * v;
                    pp = fmaf(v, av[k], pp);
                }
                pz[u] = pp;
            }
#pragma unroll
            for (int off = 16; off; off >>= 1) {         // 5 hops, in-half
#pragma unroll
                for (int u = 0; u < 4; ++u) pz[u] += __shfl_xor(pz[u], off, 64);
            }
            float w[4];
#pragma unroll
            for (int u = 0; u < 4; ++u) w[u] = val[u] ? __expf(pz[u]) : 0.f;
            l += (w[0] + w[1]) + (w[2] + w[3]);
#pragma unroll
            for (int k = 0; k < PER; ++k)
                acc[k] += fmaf(w[0], xs[0][k],
                          fmaf(w[1], xs[1][k],
                          fmaf(w[2], xs[2][k], w[3] * xs[3][k])));
        }
    }
    l += __shfl_xor(l, 32, 64);
#pragma unroll
    for (int k = 0; k < PER; ++k) acc[k] += __shfl_xor(acc[k], 32, 64);

    if (half == 0) {
        float inv = 1.f / (l + 1e-16f);
        float o[PER];
#pragma unroll
        for (int k = 0; k < PER; ++k) {
            float v = fmaf(acc[k], inv, gbias[base + k]);
            float g  = bnp[base + k], be = bnp[HC + base + k];
            float mm = bnp[2 * HC + base + k], va = bnp[3 * HC + base + k];
            v = g * (v - mm) * rsqrtf(va + 1e-5f) + be;
            o[k] = (v > 0.f) ? v : (__expf(v) - 1.f);
        }
        *(float4*)(out + (size_t)node * HC + base) = *(float4*)o;
    }
}

// ---------------------------------------------------------------------------
// K9: fused pooling + classifier, one block (128 threads) per graph
// ---------------------------------------------------------------------------
__global__ void pool_cls(const float* __restrict__ h, const int* __restrict__ gstart,
                         const float* __restrict__ w1, const float* __restrict__ b1,
                         const float* __restrict__ bnp,
                         const float* __restrict__ w2, const float* __restrict__ b2,
                         const float* __restrict__ w3, const float* __restrict__ b3,
                         float* __restrict__ out) {
    __shared__ float sg[256];
    __shared__ float sz1[128];
    __shared__ float sz2[64];
    __shared__ float sz3[2];
    int g = blockIdx.x, t = threadIdx.x;
    int a = gstart[g], b = gstart[g + 1];
    float sum = 0.f, mx = -INFINITY;
    for (int i = a; i < b; ++i) {
        float v = h[(size_t)i * 128 + t];
        sum += v;
        mx = fmaxf(mx, v);
    }
    sg[t]       = sum / fmaxf((float)(b - a), 1.f);
    sg[128 + t] = (b > a) ? mx : 0.f;
    __syncthreads();
    float acc = b1[t];
    for (int i = 0; i < 256; ++i) acc += sg[i] * w1[i * 128 + t];
    float ga = bnp[t], be = bnp[128 + t], m = bnp[256 + t], va = bnp[384 + t];
    acc = ga * (acc - m) * rsqrtf(va + 1e-5f) + be;
    sz1[t] = fmaxf(acc, 0.f);
    __syncthreads();
    if (t < 64) {
        float a2 = b2[t];
        for (int i = 0; i < 128; ++i) a2 += sz1[i] * w2[i * 64 + t];
        sz2[t] = fmaxf(a2, 0.f);
    }
    __syncthreads();
    if (t < 2) {
        float a3 = b3[t];
        for (int i = 0; i < 64; ++i) a3 += sz2[i] * w3[i * 2 + t];
        sz3[t] = a3;
    }
    __syncthreads();
    if (t < 2) {
        float mm = fmaxf(sz3[0], sz3[1]);
        float lse = mm + logf(expf(sz3[0] - mm) + expf(sz3[1] - mm));
        out[g * 2 + t] = sz3[t] - lse;
    }
}

// ---------------------------------------------------------------------------
// launch: 1 memset + 9 kernels
// ---------------------------------------------------------------------------
extern "C" void kernel_launch(void* const* d_in, const int* in_sizes, int n_in,
                              void* d_out, int out_size, void* d_ws, size_t ws_size,
                              hipStream_t stream) {
    const float* x       = (const float*)d_in[0];
    const int*   ei      = (const int*)d_in[1];
    const int*   batch   = (const int*)d_in[2];
    const float* w_in    = (const float*)d_in[3];
    const float* b_in    = (const float*)d_in[4];
    const float* bn_in   = (const float*)d_in[5];
    const float* g1_wl   = (const float*)d_in[6];
    const float* g1_bl   = (const float*)d_in[7];
    const float* g1_wr   = (const float*)d_in[8];
    const float* g1_br   = (const float*)d_in[9];
    const float* g1_att  = (const float*)d_in[10];
    const float* g1_bias = (const float*)d_in[11];
    const float* bn1     = (const float*)d_in[12];
    const float* g2_wl   = (const float*)d_in[13];
    const float* g2_bl   = (const float*)d_in[14];
    const float* g2_wr   = (const float*)d_in[15];
    const float* g2_br   = (const float*)d_in[16];
    const float* g2_att  = (const float*)d_in[17];
    const float* g2_bias = (const float*)d_in[18];
    const float* bn2     = (const float*)d_in[19];
    const float* g3_wl   = (const float*)d_in[20];
    const float* g3_bl   = (const float*)d_in[21];
    const float* g3_wr   = (const float*)d_in[22];
    const float* g3_br   = (const float*)d_in[23];
    const float* g3_att  = (const float*)d_in[24];
    const float* g3_bias = (const float*)d_in[25];
    const float* bn3     = (const float*)d_in[26];
    const float* c_w1    = (const float*)d_in[27];
    const float* c_b1    = (const float*)d_in[28];
    const float* c_bn    = (const float*)d_in[29];
    const float* c_w2    = (const float*)d_in[30];
    const float* c_b2    = (const float*)d_in[31];
    const float* c_w3    = (const float*)d_in[32];
    const float* c_b3    = (const float*)d_in[33];
    float* out = (float*)d_out;

    // ---- workspace layout
    const size_t NHC = (size_t)N_NODES * 256;
    _Float16* a16  = (_Float16*)d_ws;
    _Float16* xl16 = a16 + NHC;
    _Float16* xr16 = xl16 + NHC;
    _Float16* wt = xr16 + NHC;
    _Float16* wt1l = wt;            _Float16* wt1r = wt + 16384;
    _Float16* wt2l = wt + 32768;    _Float16* wt2r = wt + 98304;
    _Float16* wt3l = wt + 163840;   _Float16* wt3r = wt + 196608;
    float* fbase = (float*)(wt + 262144);
    float* bufD = fbase;
    int* iw = (int*)(bufD + (size_t)N_NODES * 128);
    int* deg       = iw;            int* cnt    = iw + 30000;   // contiguous pair
    int* row_start = iw + 90128;
    int* esrc      = iw + 120129;
    int* gstart    = iw + 390429;

    const int BT = 256;
    const int NT128 = cdiv(N_NODES, 128);      // 235

    // N0: zero deg+cnt
    hipMemsetAsync(deg, 0, 60000 * sizeof(int), stream);

    // K1: histogram + weight prep + input layer
    hist_wprep_input<<<1024, BT, 0, stream>>>(ei, deg, x, w_in, b_in, bn_in, a16,
                                              g1_wl, g1_wr, g2_wl, g2_wr, g3_wl, g3_wr,
                                              wt1l, wt1r, wt2l, wt2r, wt3l, wt3r);
    // K2: row_start scan + gstart binary search
    scan_all<<<NCH, 256, 0, stream>>>(deg, batch, row_start, gstart);

    // K3: GAT layer-1 GEMM + fused CSR scatter (extra y-slice)
    gemm_mfma<64, 256, 1><<<dim3(NT128, 5), 256, 0, stream>>>(
        a16, wt1l, g1_bl, wt1r, g1_br, xl16, xr16, ei, row_start, cnt, esrc, N_NODES);
    // K4: gather 1 (halved, uniform shuffles)
    gat_gather4<<<cdiv(N_NODES * 64, BT), BT, 0, stream>>>(
        xl16, xr16, row_start, esrc, g1_att, g1_bias, bn1, a16);

    // K5/K6: GAT layer 2
    gemm_mfma<256, 256, 0><<<dim3(NT128, 4), 256, 0, stream>>>(
        a16, wt2l, g2_bl, wt2r, g2_br, xl16, xr16, nullptr, nullptr, nullptr, nullptr, N_NODES);
    gat_gather4<<<cdiv(N_NODES * 64, BT), BT, 0, stream>>>(
        xl16, xr16, row_start, esrc, g2_att, g2_bias, bn2, a16);

    // K7/K8: GAT layer 3 (dual-edge gather emits f32 for pooling)
    gemm_mfma<256, 128, 0><<<dim3(NT128, 2), 256, 0, stream>>>(
        a16, wt3l, g3_bl, wt3r, g3_br, xl16, xr16, nullptr, nullptr, nullptr, nullptr, N_NODES);
    gat_gather1<<<cdiv(N_NODES * 64, BT), BT, 0, stream>>>(
        xl16, xr16, row_start, esrc, g3_att, g3_bias, bn3, bufD);

    // K9: fused pooling + classifier
    pool_cls<<<N_GRAPHS, 128, 0, stream>>>(bufD, gstart, c_w1, c_b1, c_bn,
                                           c_w2, c_b2, c_w3, c_b3, out);
}

// Round 14
// 376.505 us; speedup vs baseline: 1.0779x; 1.0069x over previous
//
#include <hip/hip_runtime.h>
#include <math.h>

#define N_NODES  30000
#define N_EDGES  240000
#define E_TOT    270000   // N_EDGES + N_NODES self loops
#define N_GRAPHS 300
#define NCH      118      // cdiv(N_NODES, 256)

typedef _Float16 half8 __attribute__((ext_vector_type(8)));
typedef _Float16 half4 __attribute__((ext_vector_type(4)));
typedef float float4v __attribute__((ext_vector_type(4)));

static inline int cdiv(int a, int b) { return (a + b - 1) / b; }

// ---------------------------------------------------------------------------
// K1: degree histogram + ALL weight transposes + input layer (K=5 GEMM).
// (deg/cnt zeroed by a hipMemsetAsync node before this kernel.)
// ---------------------------------------------------------------------------
__device__ inline void wp_dev(const float* __restrict__ W, _Float16* __restrict__ Wt,
                              int K, int CO, int gtid, int T) {
    int tot = K * CO;
    for (int i = gtid; i < tot; i += T) {
        int k = i / CO, c = i - k * CO;
        Wt[(size_t)c * K + k] = (_Float16)W[i];
    }
}

__global__ void hist_wprep_input(const int* __restrict__ ei, int* __restrict__ deg,
                                 const float* __restrict__ x, const float* __restrict__ w_in,
                                 const float* __restrict__ b_in, const float* __restrict__ bn_in,
                                 _Float16* __restrict__ a16,
                                 const float* __restrict__ w1l, const float* __restrict__ w1r,
                                 const float* __restrict__ w2l, const float* __restrict__ w2r,
                                 const float* __restrict__ w3l, const float* __restrict__ w3r,
                                 _Float16* __restrict__ t1l, _Float16* __restrict__ t1r,
                                 _Float16* __restrict__ t2l, _Float16* __restrict__ t2r,
                                 _Float16* __restrict__ t3l, _Float16* __restrict__ t3r) {
    int gtid = blockIdx.x * blockDim.x + threadIdx.x;
    int T = gridDim.x * blockDim.x;
    for (int e = gtid; e < E_TOT; e += T) {
        int d = (e < N_EDGES) ? ei[N_EDGES + e] : e - N_EDGES;
        atomicAdd(&deg[d], 1);
    }
    wp_dev(w1l, t1l, 64, 256, gtid, T);
    wp_dev(w1r, t1r, 64, 256, gtid, T);
    wp_dev(w2l, t2l, 256, 256, gtid, T);
    wp_dev(w2r, t2r, 256, 256, gtid, T);
    wp_dev(w3l, t3l, 256, 128, gtid, T);
    wp_dev(w3r, t3r, 256, 128, gtid, T);

    int lane = threadIdx.x & 63;
    int wv = blockIdx.x * (blockDim.x >> 6) + (threadIdx.x >> 6);
    int NW = gridDim.x * (blockDim.x >> 6);
    float g = bn_in[lane], be = bn_in[64 + lane];
    float m = bn_in[128 + lane], va = bn_in[192 + lane];
    float rs = rsqrtf(va + 1e-5f);
    float wcol[5];
#pragma unroll
    for (int ci = 0; ci < 5; ++ci) wcol[ci] = w_in[ci * 64 + lane];
    float bb = b_in[lane];
    for (int n = wv; n < N_NODES; n += NW) {
        float xv = (lane < 5) ? x[n * 5 + lane] : 0.f;
        float acc = bb;
#pragma unroll
        for (int ci = 0; ci < 5; ++ci)
            acc = fmaf(__shfl(xv, ci, 64), wcol[ci], acc);
        acc = g * (acc - m) * rs + be;
        a16[(size_t)n * 64 + lane] = (_Float16)fmaxf(acc, 0.f);
    }
}

// ---------------------------------------------------------------------------
// K2: one-launch scan. Block b sums deg[0..b*256) (L2-resident) + local
// chunk scan -> row_start. Block 0 binary-searches gstart (batch sorted).
// ---------------------------------------------------------------------------
__global__ __launch_bounds__(256)
void scan_all(const int* __restrict__ deg, const int* __restrict__ batch,
              int* __restrict__ row_start, int* __restrict__ gstart) {
    __shared__ int red[256];
    __shared__ int s[256];
    const int b = blockIdx.x, t = threadIdx.x;
    int pre = 0;
    for (int i = t; i < b * 256; i += 256) pre += deg[i];
    red[t] = pre;
    __syncthreads();
    for (int off = 128; off; off >>= 1) {
        if (t < off) red[t] += red[t + off];
        __syncthreads();
    }
    int base = red[0];
    int gid = b * 256 + t;
    int v = (gid < N_NODES) ? deg[gid] : 0;
    s[t] = v;
    __syncthreads();
    for (int off = 1; off < 256; off <<= 1) {
        int u = (t >= off) ? s[t - off] : 0;
        __syncthreads();
        s[t] += u;
        __syncthreads();
    }
    if (gid < N_NODES) row_start[gid] = base + s[t] - v;
    if (b == 0 && t == 0) row_start[N_NODES] = E_TOT;
    if (b == 0) {
        for (int g = t; g <= N_GRAPHS; g += 256) {
            int lo = 0, hi = N_NODES;
            while (lo < hi) {
                int mid = (lo + hi) >> 1;
                if (batch[mid] < g) lo = mid + 1;
                else                hi = mid;
            }
            gstart[g] = lo;
        }
    }
}

// ---------------------------------------------------------------------------
// MFMA f16 pair GEMM (fp32 accumulate). SCAT=1 adds a blockIdx.y slice that
// performs the CSR scatter (independent work, hides under the GEMM).
// ---------------------------------------------------------------------------
template<int K, int COUT, int SCAT>
__global__ __launch_bounds__(256, 3)
void gemm_mfma(const _Float16* __restrict__ A,
               const _Float16* __restrict__ Wtl, const float* __restrict__ bl,
               const _Float16* __restrict__ Wtr, const float* __restrict__ br,
               _Float16* __restrict__ outl, _Float16* __restrict__ outr,
               const int* __restrict__ ei, const int* __restrict__ row_start,
               int* __restrict__ cnt, int* __restrict__ esrc, int N) {
    constexpr int BM = 128, BN = 128, BK = 64;
    constexpr int LDK = BK + 8;
    constexpr int CSL = COUT / BN > 0 ? COUT / BN : 1;
    if (SCAT && blockIdx.y == 2 * CSL) {       // scatter slice
        int gtid = blockIdx.x * blockDim.x + threadIdx.x;
        int T = gridDim.x * blockDim.x;
        for (int e = gtid; e < E_TOT; e += T) {
            int s, d;
            if (e < N_EDGES) { s = ei[e]; d = ei[N_EDGES + e]; }
            else             { s = e - N_EDGES; d = s; }
            int slot = row_start[d] + atomicAdd(&cnt[d], 1);
            esrc[slot] = s;
        }
        return;
    }
    __shared__ _Float16 As[BM][LDK];
    __shared__ _Float16 Bs[BN][LDK];
    const int tid  = threadIdx.x;
    const int wave = tid >> 6;
    const int lane = tid & 63;
    const int l15  = lane & 15;
    const int lq   = lane >> 4;
    const int n0   = blockIdx.x * BM;
    const int sel  = blockIdx.y / CSL;
    const int col0 = (blockIdx.y % CSL) * BN;
    const _Float16* Wt = sel ? Wtr : Wtl;
    const float* bias  = sel ? br : bl;
    _Float16* out      = sel ? outr : outl;

    float4v acc[2][8];
#pragma unroll
    for (int mi = 0; mi < 2; ++mi)
#pragma unroll
        for (int nt = 0; nt < 8; ++nt)
#pragma unroll
            for (int r = 0; r < 4; ++r) acc[mi][nt][r] = 0.f;

    for (int kt = 0; kt < K; kt += BK) {
#pragma unroll
        for (int p = 0; p < 4; ++p) {
            int idx = p * 256 + tid;
            int row = idx >> 3;
            int ch  = (idx & 7) * 8;
            int gn  = n0 + row;
            half8 v = {};
            if (gn < N) v = *(const half8*)(A + (size_t)gn * K + kt + ch);
            *(half8*)(&As[row][ch]) = v;
        }
#pragma unroll
        for (int p = 0; p < 4; ++p) {
            int idx = p * 256 + tid;
            int row = idx >> 3;
            int ch  = (idx & 7) * 8;
            half8 v = *(const half8*)(Wt + (size_t)(col0 + row) * K + kt + ch);
            *(half8*)(&Bs[row][ch]) = v;
        }
        __syncthreads();
#pragma unroll
        for (int kk = 0; kk < BK; kk += 32) {
            half8 af0 = *(const half8*)(&As[wave * 32 + l15][kk + lq * 8]);
            half8 af1 = *(const half8*)(&As[wave * 32 + 16 + l15][kk + lq * 8]);
#pragma unroll
            for (int nt = 0; nt < 8; ++nt) {
                half8 bf = *(const half8*)(&Bs[nt * 16 + l15][kk + lq * 8]);
                acc[0][nt] = __builtin_amdgcn_mfma_f32_16x16x32_f16(af0, bf, acc[0][nt], 0, 0, 0);
                acc[1][nt] = __builtin_amdgcn_mfma_f32_16x16x32_f16(af1, bf, acc[1][nt], 0, 0, 0);
            }
        }
        __syncthreads();
    }
#pragma unroll
    for (int mi = 0; mi < 2; ++mi)
#pragma unroll
        for (int nt = 0; nt < 8; ++nt) {
            int col = col0 + nt * 16 + l15;
            float bv = bias[col];
#pragma unroll
            for (int r = 0; r < 4; ++r) {
                int row = n0 + wave * 32 + mi * 16 + lq * 4 + r;
                if (row < N)
                    out[(size_t)row * COUT + col] = (_Float16)(acc[mi][nt][r] + bv);
            }
        }
}

// ---------------------------------------------------------------------------
// GATv2 gather (H=4, HC=256): R11-measured version. One wave per node, all
// heads; 4-edge batches, each edge broadcast via UNIFORM __shfl (readlane),
// 4 independent scattered half4 loads in flight; max-free softmax (logits
// BN-bounded -> exp safe in f32); per-head dot via 4 interleaved xor hops.
// ---------------------------------------------------------------------------
__global__ __launch_bounds__(256)
void gat_gather4(const _Float16* __restrict__ xl, const _Float16* __restrict__ xr,
                 const int* __restrict__ row_start, const int* __restrict__ esrc,
                 const float* __restrict__ att, const float* __restrict__ gbias,
                 const float* __restrict__ bnp, _Float16* __restrict__ out) {
    constexpr int HC = 256, PER = 4, GROUP = 16;
    int node = (blockIdx.x * blockDim.x + threadIdx.x) >> 6;
    int lane = threadIdx.x & 63;
    if (node >= N_NODES) return;
    const int base = lane * PER;

    float rr[PER], av[PER], acc[PER];
    {
        half4 rv = *(const half4*)(xr + (size_t)node * HC + base);
#pragma unroll
        for (int k = 0; k < PER; ++k) rr[k] = (float)rv[k];
        *(float4*)av = *(const float4*)(att + base);
    }
#pragma unroll
    for (int k = 0; k < PER; ++k) acc[k] = 0.f;

    float l = 0.f;
    const int j0 = row_start[node], j1 = row_start[node + 1];
    for (int jc = j0; jc < j1; jc += 64) {
        int nedge = min(64, j1 - jc);
        int ev = (jc + lane < j1) ? esrc[jc + lane] : 0;
        for (int jj = 0; jj < nedge; jj += 4) {
            int s[4];
            bool val[4];
#pragma unroll
            for (int u = 0; u < 4; ++u) {
                int idx = jj + u;
                val[u] = idx < nedge;
                s[u] = __shfl(ev, val[u] ? idx : jj, 64);   // uniform readlane
            }
            float xs[4][PER];
#pragma unroll
            for (int u = 0; u < 4; ++u) {
                half4 xv = *(const half4*)(xl + (size_t)s[u] * HC + base);
#pragma unroll
                for (int k = 0; k < PER; ++k) xs[u][k] = (float)xv[k];
            }
            float pz[4];
#pragma unroll
            for (int u = 0; u < 4; ++u) {
                float pp = 0.f;
#pragma unroll
                for (int k = 0; k < PER; ++k) {
                    float v = xs[u][k] + rr[k];
                    v = (v > 0.f) ? v : 0.2f * v;
                    pp = fmaf(v, av[k], pp);
                }
                pz[u] = pp;
            }
#pragma unroll
            for (int off = GROUP / 2; off; off >>= 1) {
#pragma unroll
                for (int u = 0; u < 4; ++u) pz[u] += __shfl_xor(pz[u], off, 64);
            }
            float w[4];
#pragma unroll
            for (int u = 0; u < 4; ++u) w[u] = val[u] ? __expf(pz[u]) : 0.f;
            l += (w[0] + w[1]) + (w[2] + w[3]);
#pragma unroll
            for (int k = 0; k < PER; ++k)
                acc[k] += fmaf(w[0], xs[0][k],
                          fmaf(w[1], xs[1][k],
                          fmaf(w[2], xs[2][k], w[3] * xs[3][k])));
        }
    }
    float inv = 1.f / (l + 1e-16f);
    float o[PER];
#pragma unroll
    for (int k = 0; k < PER; ++k) {
        float v = fmaf(acc[k], inv, gbias[base + k]);
        float g  = bnp[base + k], be = bnp[HC + base + k];
        float mm = bnp[2 * HC + base + k], va = bnp[3 * HC + base + k];
        v = g * (v - mm) * rsqrtf(va + 1e-5f) + be;
        o[k] = (v > 0.f) ? v : (__expf(v) - 1.f);
    }
    half4 ov;
#pragma unroll
    for (int k = 0; k < PER; ++k) ov[k] = (_Float16)o[k];
    *(half4*)(out + (size_t)node * HC + base) = ov;
}

// ---------------------------------------------------------------------------
// GATv2 gather (H=1, C=128): dual-edge wave (two 32-lane halves), max-free,
// uniform shuffles + cndmask select (no bpermute on the address path).
// ---------------------------------------------------------------------------
__global__ __launch_bounds__(256)
void gat_gather1(const _Float16* __restrict__ xl, const _Float16* __restrict__ xr,
                 const int* __restrict__ row_start, const int* __restrict__ esrc,
                 const float* __restrict__ att, const float* __restrict__ gbias,
                 const float* __restrict__ bnp, float* __restrict__ out) {
    constexpr int HC = 128, PER = 4;
    int node = (blockIdx.x * blockDim.x + threadIdx.x) >> 6;
    int lane = threadIdx.x & 63;
    if (node >= N_NODES) return;
    const int half = lane >> 5;
    const int base = (lane & 31) * PER;

    float rr[PER], av[PER], acc[PER];
    {
        half4 rv = *(const half4*)(xr + (size_t)node * HC + base);
#pragma unroll
        for (int k = 0; k < PER; ++k) rr[k] = (float)rv[k];
        *(float4*)av = *(const float4*)(att + base);
    }
#pragma unroll
    for (int k = 0; k < PER; ++k) acc[k] = 0.f;

    float l = 0.f;
    const int j0 = row_start[node], j1 = row_start[node + 1];
    for (int jc = j0; jc < j1; jc += 64) {
        int nedge = min(64, j1 - jc);
        int ev = (jc + lane < j1) ? esrc[jc + lane] : 0;
        for (int jj = 0; jj < nedge; jj += 8) {          // 8 edges: 4 per half
            int s[4];
            bool val[4];
#pragma unroll
            for (int u = 0; u < 4; ++u) {
                int ia = jj + 2 * u;
                int ib = min(ia + 1, nedge - 1);
                int sa = __shfl(ev, min(ia, nedge - 1), 64);   // uniform readlane
                int sb = __shfl(ev, ib, 64);                   // uniform readlane
                s[u] = half ? sb : sa;                         // cndmask
                val[u] = (ia + half) < nedge;
            }
            float xs[4][PER];
#pragma unroll
            for (int u = 0; u < 4; ++u) {
                half4 xv = *(const half4*)(xl + (size_t)s[u] * HC + base);
#pragma unroll
                for (int k = 0; k < PER; ++k) xs[u][k] = (float)xv[k];
            }
            float pz[4];
#pragma unroll
            for (int u = 0; u < 4; ++u) {
                float pp = 0.f;
#pragma unroll
                for (int k = 0; k < PER; ++k) {
                    float v = xs[u][k] + rr[k];
                    v = (v > 0.f) ? v : 0.2f * v;
                    pp = fmaf(v, av[k], pp);
                }
                pz[u] = pp;
            }
#pragma unroll
            for (int off = 16; off; off >>= 1) {         // 5 hops, in-half
#pragma unroll
                for (int u = 0; u < 4; ++u) pz[u] += __shfl_xor(pz[u], off, 64);
            }
            float w[4];
#pragma unroll
            for (int u = 0; u < 4; ++u) w[u] = val[u] ? __expf(pz[u]) : 0.f;
            l += (w[0] + w[1]) + (w[2] + w[3]);
#pragma unroll
            for (int k = 0; k < PER; ++k)
                acc[k] += fmaf(w[0], xs[0][k],
                          fmaf(w[1], xs[1][k],
                          fmaf(w[2], xs[2][k], w[3] * xs[3][k])));
        }
    }
    l += __shfl_xor(l, 32, 64);
#pragma unroll
    for (int k = 0; k < PER; ++k) acc[k] += __shfl_xor(acc[k], 32, 64);

    if (half == 0) {
        float inv = 1.f / (l + 1e-16f);
        float o[PER];
#pragma unroll
        for (int k = 0; k < PER; ++k) {
            float v = fmaf(acc[k], inv, gbias[base + k]);
            float g  = bnp[base + k], be = bnp[HC + base + k];
            float mm = bnp[2 * HC + base + k], va = bnp[3 * HC + base + k];
            v = g * (v - mm) * rsqrtf(va + 1e-5f) + be;
            o[k] = (v > 0.f) ? v : (__expf(v) - 1.f);
        }
        *(float4*)(out + (size_t)node * HC + base) = *(float4*)o;
    }
}

// ---------------------------------------------------------------------------
// K9: fused pooling + classifier, one block (128 threads) per graph
// ---------------------------------------------------------------------------
__global__ void pool_cls(const float* __restrict__ h, const int* __restrict__ gstart,
                         const float* __restrict__ w1, const float* __restrict__ b1,
                         const float* __restrict__ bnp,
                         const float* __restrict__ w2, const float* __restrict__ b2,
                         const float* __restrict__ w3, const float* __restrict__ b3,
                         float* __restrict__ out) {
    __shared__ float sg[256];
    __shared__ float sz1[128];
    __shared__ float sz2[64];
    __shared__ float sz3[2];
    int g = blockIdx.x, t = threadIdx.x;
    int a = gstart[g], b = gstart[g + 1];
    float sum = 0.f, mx = -INFINITY;
    for (int i = a; i < b; ++i) {
        float v = h[(size_t)i * 128 + t];
        sum += v;
        mx = fmaxf(mx, v);
    }
    sg[t]       = sum / fmaxf((float)(b - a), 1.f);
    sg[128 + t] = (b > a) ? mx : 0.f;
    __syncthreads();
    float acc = b1[t];
    for (int i = 0; i < 256; ++i) acc += sg[i] * w1[i * 128 + t];
    float ga = bnp[t], be = bnp[128 + t], m = bnp[256 + t], va = bnp[384 + t];
    acc = ga * (acc - m) * rsqrtf(va + 1e-5f) + be;
    sz1[t] = fmaxf(acc, 0.f);
    __syncthreads();
    if (t < 64) {
        float a2 = b2[t];
        for (int i = 0; i < 128; ++i) a2 += sz1[i] * w2[i * 64 + t];
        sz2[t] = fmaxf(a2, 0.f);
    }
    __syncthreads();
    if (t < 2) {
        float a3 = b3[t];
        for (int i = 0; i < 64; ++i) a3 += sz2[i] * w3[i * 2 + t];
        sz3[t] = a3;
    }
    __syncthreads();
    if (t < 2) {
        float mm = fmaxf(sz3[0], sz3[1]);
        float lse = mm + logf(expf(sz3[0] - mm) + expf(sz3[1] - mm));
        out[g * 2 + t] = sz3[t] - lse;
    }
}

// ---------------------------------------------------------------------------
// launch: 1 memset + 9 kernels
// ---------------------------------------------------------------------------
extern "C" void kernel_launch(void* const* d_in, const int* in_sizes, int n_in,
                              void* d_out, int out_size, void* d_ws, size_t ws_size,
                              hipStream_t stream) {
    const float* x       = (const float*)d_in[0];
    const int*   ei      = (const int*)d_in[1];
    const int*   batch   = (const int*)d_in[2];
    const float* w_in    = (const float*)d_in[3];
    const float* b_in    = (const float*)d_in[4];
    const float* bn_in   = (const float*)d_in[5];
    const float* g1_wl   = (const float*)d_in[6];
    const float* g1_bl   = (const float*)d_in[7];
    const float* g1_wr   = (const float*)d_in[8];
    const float* g1_br   = (const float*)d_in[9];
    const float* g1_att  = (const float*)d_in[10];
    const float* g1_bias = (const float*)d_in[11];
    const float* bn1     = (const float*)d_in[12];
    const float* g2_wl   = (const float*)d_in[13];
    const float* g2_bl   = (const float*)d_in[14];
    const float* g2_wr   = (const float*)d_in[15];
    const float* g2_br   = (const float*)d_in[16];
    const float* g2_att  = (const float*)d_in[17];
    const float* g2_bias = (const float*)d_in[18];
    const float* bn2     = (const float*)d_in[19];
    const float* g3_wl   = (const float*)d_in[20];
    const float* g3_bl   = (const float*)d_in[21];
    const float* g3_wr   = (const float*)d_in[22];
    const float* g3_br   = (const float*)d_in[23];
    const float* g3_att  = (const float*)d_in[24];
    const float* g3_bias = (const float*)d_in[25];
    const float* bn3     = (const float*)d_in[26];
    const float* c_w1    = (const float*)d_in[27];
    const float* c_b1    = (const float*)d_in[28];
    const float* c_bn    = (const float*)d_in[29];
    const float* c_w2    = (const float*)d_in[30];
    const float* c_b2    = (const float*)d_in[31];
    const float* c_w3    = (const float*)d_in[32];
    const float* c_b3    = (const float*)d_in[33];
    float* out = (float*)d_out;

    // ---- workspace layout
    const size_t NHC = (size_t)N_NODES * 256;
    _Float16* a16  = (_Float16*)d_ws;
    _Float16* xl16 = a16 + NHC;
    _Float16* xr16 = xl16 + NHC;
    _Float16* wt = xr16 + NHC;
    _Float16* wt1l = wt;            _Float16* wt1r = wt + 16384;
    _Float16* wt2l = wt + 32768;    _Float16* wt2r = wt + 98304;
    _Float16* wt3l = wt + 163840;   _Float16* wt3r = wt + 196608;
    float* fbase = (float*)(wt + 262144);
    float* bufD = fbase;
    int* iw = (int*)(bufD + (size_t)N_NODES * 128);
    int* deg       = iw;            int* cnt    = iw + 30000;   // contiguous pair
    int* row_start = iw + 90128;
    int* esrc      = iw + 120129;
    int* gstart    = iw + 390429;

    const int BT = 256;
    const int NT128 = cdiv(N_NODES, 128);      // 235

    // N0: zero deg+cnt
    hipMemsetAsync(deg, 0, 60000 * sizeof(int), stream);

    // K1: histogram + weight prep + input layer
    hist_wprep_input<<<1024, BT, 0, stream>>>(ei, deg, x, w_in, b_in, bn_in, a16,
                                              g1_wl, g1_wr, g2_wl, g2_wr, g3_wl, g3_wr,
                                              wt1l, wt1r, wt2l, wt2r, wt3l, wt3r);
    // K2: row_start scan + gstart binary search
    scan_all<<<NCH, 256, 0, stream>>>(deg, batch, row_start, gstart);

    // K3: GAT layer-1 GEMM + fused CSR scatter (extra y-slice)
    gemm_mfma<64, 256, 1><<<dim3(NT128, 5), 256, 0, stream>>>(
        a16, wt1l, g1_bl, wt1r, g1_br, xl16, xr16, ei, row_start, cnt, esrc, N_NODES);
    // K4: gather 1 (R11-measured full-wave 4-edge version)
    gat_gather4<<<cdiv(N_NODES * 64, BT), BT, 0, stream>>>(
        xl16, xr16, row_start, esrc, g1_att, g1_bias, bn1, a16);

    // K5/K6: GAT layer 2
    gemm_mfma<256, 256, 0><<<dim3(NT128, 4), 256, 0, stream>>>(
        a16, wt2l, g2_bl, wt2r, g2_br, xl16, xr16, nullptr, nullptr, nullptr, nullptr, N_NODES);
    gat_gather4<<<cdiv(N_NODES * 64, BT), BT, 0, stream>>>(
        xl16, xr16, row_start, esrc, g2_att, g2_bias, bn2, a16);

    // K7/K8: GAT layer 3 (dual-edge gather emits f32 for pooling)
    gemm_mfma<256, 128, 0><<<dim3(NT128, 2), 256, 0, stream>>>(
        a16, wt3l, g3_bl, wt3r, g3_br, xl16, xr16, nullptr, nullptr, nullptr, nullptr, N_NODES);
    gat_gather1<<<cdiv(N_NODES * 64, BT), BT, 0, stream>>>(
        xl16, xr16, row_start, esrc, g3_att, g3_bias, bn3, bufD);

    // K9: fused pooling + classifier
    pool_cls<<<N_GRAPHS, 128, 0, stream>>>(bufD, gstart, c_w1, c_b1, c_bn,
                                           c_w2, c_b2, c_w3, c_b3, out);
}